// Round 5
// baseline (237.477 us; speedup 1.0000x reference)
//
#include <hip/hip_runtime.h>
#include <hip/hip_bf16.h>

#define N_NODES 20000
#define DIM 128
#define N_EDGES 500000
#define BATCH 16384
#define EPS 1e-6f
#define L2E 1.4426950408889634f

typedef _Float16 half8 __attribute__((ext_vector_type(8)));
typedef _Float16 half4_t __attribute__((ext_vector_type(4)));
typedef float f32x4 __attribute__((ext_vector_type(4)));

__device__ __forceinline__ float fast_sqrtf(float x) {
#if __has_builtin(__builtin_amdgcn_sqrtf)
    return __builtin_amdgcn_sqrtf(x);
#else
    return sqrtf(x);
#endif
}
__device__ __forceinline__ float fast_exp2f(float x) {
#if __has_builtin(__builtin_amdgcn_exp2f)
    return __builtin_amdgcn_exp2f(x);
#else
    return exp2f(x);
#endif
}

// ---- grid composition: 1D main grid, 4 tile blocks : 1 link block ----
#define NB_TILE 16512      // 4128*4 = number of 128x64 triu tiles (exact)
#define NB_LINKB 4128
#define NB_MAIN 20640      // 4128*5
#define LINK_EPB 128       // edges per link block (4128*128 >= 500000)
#define NB_FIN 128

// ---- workspace layout (bytes) ----
#define OFF_PGEMM 0
#define OFF_PLINK 66048
#define OFF_FPART 82560
#define OFF_PSH   83072            // A: gathered p_star rows, fp16 (16384*128*2)
#define OFF_PPH   4277376          // B: gathered p rows, fp16
#define OFF_N2S   8471680
#define OFF_N2P   8537216
#define OFF_BPS   8602752          // l2e-scaled gathered beta_p_star
#define OFF_BP    8668288          // l2e-scaled gathered beta_p
#define OFF_P16   8733824          // full fp16 p table (20000*128*2)
#define OFF_PS16  13853824         // full fp16 p_star table
#define OFF_END   18973824

// Fused prep: 2 gathers (batch rows -> fp16 + norms + l2e*beta) and 2 full-table
// fp16 conversions. 8 rows/block.
__global__ __launch_bounds__(256) void prep_kernel(
    const float* __restrict__ p, const float* __restrict__ p_star,
    const float* __restrict__ beta_p, const float* __restrict__ beta_ps,
    const int* __restrict__ nodes_ps, const int* __restrict__ nodes_p,
    _Float16* __restrict__ Ah, float* __restrict__ n2A, float* __restrict__ bA2,
    _Float16* __restrict__ Bh, float* __restrict__ n2B, float* __restrict__ bB2,
    _Float16* __restrict__ p16, _Float16* __restrict__ ps16)
{
    const int bx = blockIdx.x;
    const int g = threadIdx.x & 31;
    const int r8 = threadIdx.x >> 5;
    if (bx < 4096) {
        const bool isA = bx < 2048;
        int row = (isA ? bx : bx - 2048) * 8 + r8;
        int id = isA ? nodes_ps[row] : nodes_p[row];
        const float* src = isA ? p_star : p;
        float4 v = ((const float4*)(src + (size_t)id * DIM))[g];
        half4_t o;
        o[0] = (_Float16)v.x; o[1] = (_Float16)v.y; o[2] = (_Float16)v.z; o[3] = (_Float16)v.w;
        _Float16* dst = isA ? Ah : Bh;
        *(half4_t*)(dst + (size_t)row * DIM + g * 4) = o;
        float nrm = v.x * v.x + v.y * v.y + v.z * v.z + v.w * v.w;
        #pragma unroll
        for (int m = 16; m >= 1; m >>= 1) nrm += __shfl_xor(nrm, m, 32);
        if (g == 0) {
            if (isA) { n2A[row] = nrm; bA2[row] = L2E * beta_ps[id]; }
            else     { n2B[row] = nrm; bB2[row] = L2E * beta_p[id]; }
        }
    } else {
        const bool isP = bx < 6596;
        int row = (isP ? bx - 4096 : bx - 6596) * 8 + r8;
        const float* src = isP ? p : p_star;
        _Float16* dst = isP ? p16 : ps16;
        float4 v = ((const float4*)(src + (size_t)row * DIM))[g];
        half4_t o;
        o[0] = (_Float16)v.x; o[1] = (_Float16)v.y; o[2] = (_Float16)v.z; o[3] = (_Float16)v.w;
        *(half4_t*)(dst + (size_t)row * DIM + g * 4) = o;
    }
}

// Fused main kernel: 1D grid of 20640 blocks; every 5th block handles 128 edges
// of the link term, the rest are 128x64 non-link tiles (3 blocks/CU @ 52KB LDS).
__global__ __launch_bounds__(256) void main_kernel(
    const _Float16* __restrict__ Ag, const _Float16* __restrict__ Bg,
    const float* __restrict__ n2A, const float* __restrict__ n2B,
    const float* __restrict__ bA2, const float* __restrict__ bB2,
    const int* __restrict__ edges,
    const float* __restrict__ beta_p, const float* __restrict__ beta_ps,
    const _Float16* __restrict__ p16, const _Float16* __restrict__ ps16,
    const float* __restrict__ pf, const float* __restrict__ psf, int use16,
    float* __restrict__ pgemm, float* __restrict__ plink)
{
    const int f = blockIdx.x;
    const int grp5 = f / 5, rem5 = f % 5;
    const int tid = threadIdx.x;

    __shared__ __align__(16) _Float16 As[128][136];   // +8 pad: 2-way bank aliasing (free)
    __shared__ __align__(16) _Float16 Bs[64][136];
    __shared__ float smr[4];

    if (rem5 == 4) {
        // ---------------- link block ----------------
        float tacc = 0.f;
        if (use16) {
            int g = tid & 15, grp = tid >> 4;       // 16 lanes/edge, 16 edges/pass
            #pragma unroll
            for (int t = 0; t < 8; ++t) {
                int e = grp5 * LINK_EPB + t * 16 + grp;
                if (e < N_EDGES) {
                    int e0 = edges[e];
                    int e1 = edges[N_EDGES + e];
                    half8 a = *(const half8*)(p16 + (size_t)e0 * DIM + g * 8);
                    half8 b = *(const half8*)(ps16 + (size_t)e1 * DIM + g * 8);
                    float s = 0.f;
                    #pragma unroll
                    for (int k = 0; k < 8; ++k) {
                        float d = (float)a[k] - (float)b[k] + EPS;
                        s = fmaf(d, d, s);
                    }
                    #pragma unroll
                    for (int m = 8; m >= 1; m >>= 1) s += __shfl_xor(s, m, 16);
                    if (g == 0) tacc += (beta_ps[e0] + beta_p[e1]) - fast_sqrtf(s);
                }
            }
        } else {
            int g = tid & 31, grp = tid >> 5;       // 32 lanes/edge fp32 fallback
            #pragma unroll
            for (int t = 0; t < 16; ++t) {
                int e = grp5 * LINK_EPB + t * 8 + grp;
                if (e < N_EDGES) {
                    int e0 = edges[e];
                    int e1 = edges[N_EDGES + e];
                    float4 a = ((const float4*)(pf + (size_t)e0 * DIM))[g];
                    float4 b = ((const float4*)(psf + (size_t)e1 * DIM))[g];
                    float dx = a.x - b.x + EPS, dy = a.y - b.y + EPS;
                    float dz = a.z - b.z + EPS, dw = a.w - b.w + EPS;
                    float s = dx * dx + dy * dy + dz * dz + dw * dw;
                    #pragma unroll
                    for (int m = 16; m >= 1; m >>= 1) s += __shfl_xor(s, m, 32);
                    if (g == 0) tacc += (beta_ps[e0] + beta_p[e1]) - fast_sqrtf(s);
                }
            }
        }
        #pragma unroll
        for (int m = 32; m >= 1; m >>= 1) tacc += __shfl_xor(tacc, m, 64);
        if ((tid & 63) == 0) smr[tid >> 6] = tacc;
        __syncthreads();
        if (tid == 0) plink[grp5] = smr[0] + smr[1] + smr[2] + smr[3];
        return;
    }

    // ---------------- non-link tile block ----------------
    const int t = grp5 * 4 + rem5;            // tile index in [0, 16512)
    const int by = t / 258, bx = t % 258;
    // wrapped triangle over 128 i-tiles (128 rows) x 256 j-tiles (64 cols):
    // row ti has 256-2*ti tiles (tj >= 2*ti); pair ti=by with ti=127-by.
    int ti, tj;
    const int len = 256 - 2 * by;
    if (bx < len) { ti = by; tj = 2 * by + bx; }
    else          { ti = 127 - by; tj = bx - 2; }
    const int i0 = ti * 128;
    const int j0 = tj * 64;

    const int lane = tid & 63;
    const int w = tid >> 6;
    const int wm = w & 1;         // wave i-half (64 rows)
    const int wn = w >> 1;        // wave j-half (32 cols)
    const int quad = lane >> 4;
    const int lr = lane & 15;
    const int ilo = i0 + wm * 64;
    const int jlo = j0 + wn * 32;

    // hoist all epilogue operands now -- latency hidden behind staging
    float4 n2i[4], bi[4];
    float n2j[2], bj[2];
    #pragma unroll
    for (int mi = 0; mi < 4; ++mi) {
        n2i[mi] = *(const float4*)&n2A[ilo + mi * 16 + quad * 4];
        bi[mi] = *(const float4*)&bA2[ilo + mi * 16 + quad * 4];
    }
    #pragma unroll
    for (int ni = 0; ni < 2; ++ni) {
        n2j[ni] = n2B[jlo + ni * 16 + lr];
        bj[ni] = bB2[jlo + ni * 16 + lr];
    }

    // stage tiles (lane->(row=c>>4, chunk=c&15): uniform 8 words/bank, minimal)
    #pragma unroll
    for (int c = tid; c < 2048; c += 256)
        *(uint4*)&As[c >> 4][(c & 15) * 8] =
            *(const uint4*)(Ag + (size_t)(i0 + (c >> 4)) * DIM + (c & 15) * 8);
    #pragma unroll
    for (int c = tid; c < 1024; c += 256)
        *(uint4*)&Bs[c >> 4][(c & 15) * 8] =
            *(const uint4*)(Bg + (size_t)(j0 + (c >> 4)) * DIM + (c & 15) * 8);
    __syncthreads();

    const bool dead = (jlo + 31 <= ilo);      // all j <= i
    const bool freew = (jlo > ilo + 63);      // all j > i

    float lsum = 0.f;
    if (!dead) {
        f32x4 acc[4][2] = {};
        #pragma unroll
        for (int ks = 0; ks < 4; ++ks) {
            int koff = ks * 32 + quad * 8;
            half8 af[4], bf[2];
            #pragma unroll
            for (int u = 0; u < 4; ++u) af[u] = *(const half8*)&As[wm * 64 + u * 16 + lr][koff];
            #pragma unroll
            for (int u = 0; u < 2; ++u) bf[u] = *(const half8*)&Bs[wn * 32 + u * 16 + lr][koff];
            #pragma unroll
            for (int mi = 0; mi < 4; ++mi)
                #pragma unroll
                for (int ni = 0; ni < 2; ++ni)
                    acc[mi][ni] = __builtin_amdgcn_mfma_f32_16x16x32_f16(af[mi], bf[ni], acc[mi][ni], 0, 0, 0);
        }

        // epilogue: C/D layout col=lane&15, row=quad*4+reg; all operands in regs
        if (freew) {
            #pragma unroll
            for (int mi = 0; mi < 4; ++mi)
                #pragma unroll
                for (int ni = 0; ni < 2; ++ni) {
                    f32x4 d = acc[mi][ni];
                    #pragma unroll
                    for (int r = 0; r < 4; ++r) {
                        float tt = ((const float*)&n2i[mi])[r] + n2j[ni];
                        float sq = fmaxf(fmaf(d[r], -2.f, tt), 0.f);
                        float dist = fast_sqrtf(sq);
                        float arg = fmaf(dist, -L2E, ((const float*)&bi[mi])[r] + bj[ni]);
                        lsum += fast_exp2f(arg);
                    }
                }
        } else {
            #pragma unroll
            for (int mi = 0; mi < 4; ++mi)
                #pragma unroll
                for (int ni = 0; ni < 2; ++ni) {
                    f32x4 d = acc[mi][ni];
                    #pragma unroll
                    for (int r = 0; r < 4; ++r) {
                        int ig = ilo + mi * 16 + quad * 4 + r;
                        int jg = jlo + ni * 16 + lr;
                        float tt = ((const float*)&n2i[mi])[r] + n2j[ni];
                        float sq = fmaxf(fmaf(d[r], -2.f, tt), 0.f);
                        float dist = fast_sqrtf(sq);
                        float arg = fmaf(dist, -L2E, ((const float*)&bi[mi])[r] + bj[ni]);
                        float ex = fast_exp2f(arg);
                        if (jg > ig) lsum += ex;
                    }
                }
        }
    }

    #pragma unroll
    for (int m = 32; m >= 1; m >>= 1) lsum += __shfl_xor(lsum, m, 64);
    if (lane == 0) smr[w] = lsum;
    __syncthreads();
    if (tid == 0) pgemm[t] = smr[0] + smr[1] + smr[2] + smr[3];
}

__global__ __launch_bounds__(256) void reduce1_kernel(
    const float* __restrict__ pg, const float* __restrict__ pl, float* __restrict__ fpart)
{
    float s = 0.f;
    for (int k = blockIdx.x * 256 + threadIdx.x; k < NB_TILE; k += NB_FIN * 256) s += pg[k];
    for (int k = blockIdx.x * 256 + threadIdx.x; k < NB_LINKB; k += NB_FIN * 256) s -= pl[k];
    #pragma unroll
    for (int m = 32; m >= 1; m >>= 1) s += __shfl_xor(s, m, 64);
    __shared__ float sm[4];
    int w = threadIdx.x >> 6;
    if ((threadIdx.x & 63) == 0) sm[w] = s;
    __syncthreads();
    if (threadIdx.x == 0) fpart[blockIdx.x] = sm[0] + sm[1] + sm[2] + sm[3];
}

__global__ __launch_bounds__(128) void reduce2_kernel(
    const float* __restrict__ fpart, float* __restrict__ out)
{
    float s = fpart[threadIdx.x];
    #pragma unroll
    for (int m = 32; m >= 1; m >>= 1) s += __shfl_xor(s, m, 64);
    __shared__ float sm[2];
    if ((threadIdx.x & 63) == 0) sm[threadIdx.x >> 6] = s;
    __syncthreads();
    if (threadIdx.x == 0) out[0] = sm[0] + sm[1];
}

extern "C" void kernel_launch(void* const* d_in, const int* in_sizes, int n_in,
                              void* d_out, int out_size, void* d_ws, size_t ws_size,
                              hipStream_t stream) {
    const int* edges = (const int*)d_in[0];
    const int* nodes_p_star = (const int*)d_in[1];
    const int* nodes_p = (const int*)d_in[2];
    const float* beta_p = (const float*)d_in[3];
    const float* beta_p_star = (const float*)d_in[4];
    const float* p = (const float*)d_in[5];
    const float* p_star = (const float*)d_in[6];

    char* ws = (char*)d_ws;
    float* pgemm = (float*)(ws + OFF_PGEMM);
    float* plink = (float*)(ws + OFF_PLINK);
    float* fpart = (float*)(ws + OFF_FPART);
    _Float16* psh = (_Float16*)(ws + OFF_PSH);
    _Float16* pph = (_Float16*)(ws + OFF_PPH);
    float* n2s = (float*)(ws + OFF_N2S);
    float* n2p = (float*)(ws + OFF_N2P);
    float* bps2 = (float*)(ws + OFF_BPS);
    float* bp2 = (float*)(ws + OFF_BP);
    _Float16* p16 = (_Float16*)(ws + OFF_P16);
    _Float16* ps16 = (_Float16*)(ws + OFF_PS16);

    const int use16 = (ws_size >= (size_t)OFF_END) ? 1 : 0;

    prep_kernel<<<9096, 256, 0, stream>>>(
        p, p_star, beta_p, beta_p_star, nodes_p_star, nodes_p,
        psh, n2s, bps2, pph, n2p, bp2, p16, ps16);

    main_kernel<<<NB_MAIN, 256, 0, stream>>>(
        psh, pph, n2s, n2p, bps2, bp2,
        edges, beta_p, beta_p_star, p16, ps16, p, p_star, use16,
        pgemm, plink);

    reduce1_kernel<<<NB_FIN, 256, 0, stream>>>(pgemm, plink, fpart);
    reduce2_kernel<<<1, 128, 0, stream>>>(fpart, (float*)d_out);
}

// Round 6
// 193.449 us; speedup vs baseline: 1.2276x; 1.2276x over previous
//
#include <hip/hip_runtime.h>
#include <hip/hip_bf16.h>

#define N_NODES 20000
#define DIM 128
#define N_EDGES 500000
#define BATCH 16384
#define EPS 1e-6f
#define L2E 1.4426950408889634f

typedef _Float16 half8 __attribute__((ext_vector_type(8)));
typedef _Float16 half4_t __attribute__((ext_vector_type(4)));
typedef float f32x4 __attribute__((ext_vector_type(4)));

__device__ __forceinline__ float fast_sqrtf(float x) {
#if __has_builtin(__builtin_amdgcn_sqrtf)
    return __builtin_amdgcn_sqrtf(x);
#else
    return sqrtf(x);
#endif
}
__device__ __forceinline__ float fast_exp2f(float x) {
#if __has_builtin(__builtin_amdgcn_exp2f)
    return __builtin_amdgcn_exp2f(x);
#else
    return exp2f(x);
#endif
}

#define NB_TILE 8256               // 129*64 wrapped-triangle 128x128 tiles

// ---- workspace layout (bytes) ----
#define OFF_PGEMM 0                // 8256*4 = 33024
#define OFF_PSH   33280            // A: gathered p_star rows fp16 (16384*128*2)
#define OFF_PPH   4227584
#define OFF_N2S   8421888
#define OFF_N2P   8487424
#define OFF_BPS   8552960          // L2E * beta_p_star gathered
#define OFF_BP    8618496          // L2E * beta_p gathered
#define OFF_P16   8684032          // full fp16 p (20000*128*2)
#define OFF_PS16  13804032         // full fp16 p_star
#define OFF_END   18924032

// Fused prep: 2 gathers (rows->fp16 + norms + L2E*beta) and 2 full-table fp16 converts.
__global__ __launch_bounds__(256) void prep_kernel(
    const float* __restrict__ p, const float* __restrict__ p_star,
    const float* __restrict__ beta_p, const float* __restrict__ beta_ps,
    const int* __restrict__ nodes_ps, const int* __restrict__ nodes_p,
    _Float16* __restrict__ Ah, float* __restrict__ n2A, float* __restrict__ bA2,
    _Float16* __restrict__ Bh, float* __restrict__ n2B, float* __restrict__ bB2,
    _Float16* __restrict__ p16, _Float16* __restrict__ ps16)
{
    const int bx = blockIdx.x;
    const int g = threadIdx.x & 31;
    const int r8 = threadIdx.x >> 5;
    if (bx < 4096) {
        const bool isA = bx < 2048;
        int row = (isA ? bx : bx - 2048) * 8 + r8;
        int id = isA ? nodes_ps[row] : nodes_p[row];
        const float* src = isA ? p_star : p;
        float4 v = ((const float4*)(src + (size_t)id * DIM))[g];
        half4_t o;
        o[0] = (_Float16)v.x; o[1] = (_Float16)v.y; o[2] = (_Float16)v.z; o[3] = (_Float16)v.w;
        _Float16* dst = isA ? Ah : Bh;
        *(half4_t*)(dst + (size_t)row * DIM + g * 4) = o;
        float nrm = v.x * v.x + v.y * v.y + v.z * v.z + v.w * v.w;
        #pragma unroll
        for (int m = 16; m >= 1; m >>= 1) nrm += __shfl_xor(nrm, m, 32);
        if (g == 0) {
            if (isA) { n2A[row] = nrm; bA2[row] = L2E * beta_ps[id]; }
            else     { n2B[row] = nrm; bB2[row] = L2E * beta_p[id]; }
        }
    } else {
        const bool isP = bx < 6596;
        int row = (isP ? bx - 4096 : bx - 6596) * 8 + r8;
        const float* src = isP ? p : p_star;
        _Float16* dst = isP ? p16 : ps16;
        float4 v = ((const float4*)(src + (size_t)row * DIM))[g];
        half4_t o;
        o[0] = (_Float16)v.x; o[1] = (_Float16)v.y; o[2] = (_Float16)v.z; o[3] = (_Float16)v.w;
        *(half4_t*)(dst + (size_t)row * DIM + g * 4) = o;
    }
}

// Main: 8256 blocks of 512 threads. Each block: one 128x128 non-link tile
// (8 waves x 32x64 subtile) + 64 link edges (8/wave), uniformly fused.
__global__ __launch_bounds__(512, 4) void main_kernel(
    const _Float16* __restrict__ Ag, const _Float16* __restrict__ Bg,
    const float* __restrict__ n2A, const float* __restrict__ n2B,
    const float* __restrict__ bA2, const float* __restrict__ bB2,
    const int* __restrict__ edges,
    const float* __restrict__ beta_p, const float* __restrict__ beta_ps,
    const _Float16* __restrict__ p16, const _Float16* __restrict__ ps16,
    const float* __restrict__ pf, const float* __restrict__ psf, int use16,
    float* __restrict__ pgemm)
{
    const int bx = blockIdx.x, by = blockIdx.y;   // grid (129, 64)
    int ti, tj;
    const int len = 128 - by;
    if (bx < len) { ti = by; tj = by + bx; }
    else          { ti = 127 - by; tj = 127 - (bx - len); }
    const int i0 = ti * 128, j0 = tj * 128;
    const int bid = by * 129 + bx;
    const bool diag = (ti == tj);

    __shared__ __align__(16) _Float16 As[128][136];  // +8 pad, 272B stride
    __shared__ __align__(16) _Float16 Bs[128][136];
    __shared__ float smr[8];

    const int tid = threadIdx.x;
    const int lane = tid & 63;
    const int w = tid >> 6;       // 0..7
    const int wm = w & 3;         // 32-row quarter
    const int wn = w >> 2;        // 64-col half
    const int quad = lane >> 4;
    const int lr = lane & 15;

    // ---- link edges: issue loads first (drained by the staging barrier) ----
    float lsum = 0.f;
    half8 ea[2], eb[2];
    float ebeta[2] = {0.f, 0.f};
    bool ev[2];
    {
        #pragma unroll
        for (int t = 0; t < 2; ++t) {
            int e = bid * 64 + w * 8 + quad * 2 + t;
            ev[t] = (e < N_EDGES);
            if (ev[t]) {
                int e0 = edges[e];
                int e1 = edges[N_EDGES + e];
                if (use16) {
                    ea[t] = *(const half8*)(p16 + (size_t)e0 * DIM + lr * 8);
                    eb[t] = *(const half8*)(ps16 + (size_t)e1 * DIM + lr * 8);
                    if (lr == 0) ebeta[t] = beta_ps[e0] + beta_p[e1];
                } else {
                    // fp32 fallback: compute inline (safety path)
                    const float* ar = pf + (size_t)e0 * DIM + lr * 8;
                    const float* br = psf + (size_t)e1 * DIM + lr * 8;
                    float s = 0.f;
                    #pragma unroll
                    for (int k = 0; k < 8; ++k) {
                        float d = ar[k] - br[k] + EPS;
                        s = fmaf(d, d, s);
                    }
                    #pragma unroll
                    for (int m = 8; m >= 1; m >>= 1) s += __shfl_xor(s, m, 16);
                    if (lr == 0) lsum -= (beta_ps[e0] + beta_p[e1]) - fast_sqrtf(s);
                }
            }
        }
    }

    // ---- hoisted epilogue operands (latency hidden behind staging) ----
    const int ilo = i0 + wm * 32, jlo = j0 + wn * 64;
    float4 n2i[2], bi[2];
    #pragma unroll
    for (int mi = 0; mi < 2; ++mi) {
        n2i[mi] = *(const float4*)&n2A[ilo + mi * 16 + quad * 4];
        bi[mi]  = *(const float4*)&bA2[ilo + mi * 16 + quad * 4];
    }
    float n2j[4], bj[4];
    #pragma unroll
    for (int ni = 0; ni < 4; ++ni) {
        n2j[ni] = n2B[jlo + ni * 16 + lr];
        bj[ni]  = bB2[jlo + ni * 16 + lr];
    }

    // ---- stage tiles: 2048 16B chunks per array, 4 per thread per array ----
    #pragma unroll
    for (int c = tid; c < 2048; c += 512) {
        int row = c >> 4, col = (c & 15) * 8;
        *(uint4*)&As[row][col] = *(const uint4*)(Ag + (size_t)(i0 + row) * DIM + col);
        *(uint4*)&Bs[row][col] = *(const uint4*)(Bg + (size_t)(j0 + row) * DIM + col);
    }
    __syncthreads();

    // wave class on diagonal tiles: rows [wm*32,+32) vs cols [wn*64,+64)
    int cls = 0;  // 0=free (all j>i), 1=masked, 2=dead
    if (diag) cls = (wn == 0) ? (wm >= 2 ? 2 : 1) : (wm >= 2 ? 1 : 0);

    if (cls != 2) {
        f32x4 acc[2][4] = {};
        #pragma unroll
        for (int ks = 0; ks < 4; ++ks) {
            int koff = ks * 32 + quad * 8;
            half8 af[2], bf[4];
            #pragma unroll
            for (int u = 0; u < 2; ++u) af[u] = *(const half8*)&As[wm * 32 + u * 16 + lr][koff];
            #pragma unroll
            for (int v = 0; v < 4; ++v) bf[v] = *(const half8*)&Bs[wn * 64 + v * 16 + lr][koff];
            #pragma unroll
            for (int mi = 0; mi < 2; ++mi)
                #pragma unroll
                for (int ni = 0; ni < 4; ++ni)
                    acc[mi][ni] = __builtin_amdgcn_mfma_f32_16x16x32_f16(af[mi], bf[ni], acc[mi][ni], 0, 0, 0);
        }

        // epilogue: C/D layout col=lane&15, row=quad*4+reg
        if (cls == 0) {
            #pragma unroll
            for (int mi = 0; mi < 2; ++mi)
                #pragma unroll
                for (int ni = 0; ni < 4; ++ni) {
                    f32x4 d = acc[mi][ni];
                    #pragma unroll
                    for (int r = 0; r < 4; ++r) {
                        float tt = ((const float*)&n2i[mi])[r] + n2j[ni];
                        float sq = fmaxf(fmaf(d[r], -2.f, tt), 0.f);
                        float arg = fmaf(fast_sqrtf(sq), -L2E, ((const float*)&bi[mi])[r] + bj[ni]);
                        lsum += fast_exp2f(arg);
                    }
                }
        } else {
            #pragma unroll
            for (int mi = 0; mi < 2; ++mi)
                #pragma unroll
                for (int ni = 0; ni < 4; ++ni) {
                    f32x4 d = acc[mi][ni];
                    #pragma unroll
                    for (int r = 0; r < 4; ++r) {
                        int ig = ilo + mi * 16 + quad * 4 + r;
                        int jg = jlo + ni * 16 + lr;
                        float tt = ((const float*)&n2i[mi])[r] + n2j[ni];
                        float sq = fmaxf(fmaf(d[r], -2.f, tt), 0.f);
                        float arg = fmaf(fast_sqrtf(sq), -L2E, ((const float*)&bi[mi])[r] + bj[ni]);
                        float ex = fast_exp2f(arg);
                        if (jg > ig) lsum += ex;
                    }
                }
        }
    }

    // ---- link math (fp16 path): data long since arrived ----
    if (use16) {
        #pragma unroll
        for (int t = 0; t < 2; ++t) {
            if (ev[t]) {
                float s = 0.f;
                #pragma unroll
                for (int k = 0; k < 8; ++k) {
                    float d = (float)ea[t][k] - (float)eb[t][k] + EPS;
                    s = fmaf(d, d, s);
                }
                #pragma unroll
                for (int m = 8; m >= 1; m >>= 1) s += __shfl_xor(s, m, 16);
                if (lr == 0) lsum -= ebeta[t] - fast_sqrtf(s);
            }
        }
    }

    #pragma unroll
    for (int m = 32; m >= 1; m >>= 1) lsum += __shfl_xor(lsum, m, 64);
    if (lane == 0) smr[w] = lsum;
    __syncthreads();
    if (tid == 0) {
        float t = 0.f;
        #pragma unroll
        for (int i = 0; i < 8; ++i) t += smr[i];
        pgemm[bid] = t;
    }
}

// single-block final reduction over 8256 partials
__global__ __launch_bounds__(1024) void reduce_kernel(
    const float* __restrict__ pg, float* __restrict__ out)
{
    float s = 0.f;
    for (int k = threadIdx.x; k < NB_TILE; k += 1024) s += pg[k];
    #pragma unroll
    for (int m = 32; m >= 1; m >>= 1) s += __shfl_xor(s, m, 64);
    __shared__ float sm[16];
    if ((threadIdx.x & 63) == 0) sm[threadIdx.x >> 6] = s;
    __syncthreads();
    if (threadIdx.x == 0) {
        float t = 0.f;
        #pragma unroll
        for (int i = 0; i < 16; ++i) t += sm[i];
        out[0] = t;
    }
}

extern "C" void kernel_launch(void* const* d_in, const int* in_sizes, int n_in,
                              void* d_out, int out_size, void* d_ws, size_t ws_size,
                              hipStream_t stream) {
    const int* edges = (const int*)d_in[0];
    const int* nodes_p_star = (const int*)d_in[1];
    const int* nodes_p = (const int*)d_in[2];
    const float* beta_p = (const float*)d_in[3];
    const float* beta_p_star = (const float*)d_in[4];
    const float* p = (const float*)d_in[5];
    const float* p_star = (const float*)d_in[6];

    char* ws = (char*)d_ws;
    float* pgemm = (float*)(ws + OFF_PGEMM);
    _Float16* psh = (_Float16*)(ws + OFF_PSH);
    _Float16* pph = (_Float16*)(ws + OFF_PPH);
    float* n2s = (float*)(ws + OFF_N2S);
    float* n2p = (float*)(ws + OFF_N2P);
    float* bps2 = (float*)(ws + OFF_BPS);
    float* bp2 = (float*)(ws + OFF_BP);
    _Float16* p16 = (_Float16*)(ws + OFF_P16);
    _Float16* ps16 = (_Float16*)(ws + OFF_PS16);

    const int use16 = (ws_size >= (size_t)OFF_END) ? 1 : 0;

    prep_kernel<<<9096, 256, 0, stream>>>(
        p, p_star, beta_p, beta_p_star, nodes_p_star, nodes_p,
        psh, n2s, bps2, pph, n2p, bp2, p16, ps16);

    main_kernel<<<dim3(129, 64), 512, 0, stream>>>(
        psh, pph, n2s, n2p, bps2, bp2,
        edges, beta_p, beta_p_star, p16, ps16, p, p_star, use16,
        pgemm);

    reduce_kernel<<<1, 1024, 0, stream>>>(pgemm, (float*)d_out);
}